// Round 8
// baseline (273.323 us; speedup 1.0000x reference)
//
#include <hip/hip_runtime.h>
#include <math.h>

// Problem constants: B=512, C=50000, D=256.
#define D_DIM 256
#define TM 128
#define TN 128
#define BK 32     // K-tile depth (bf16); 8 K-iterations
#define NBP 392   // padded partial stride (NB=391)

typedef __attribute__((ext_vector_type(8))) short short8;
typedef __attribute__((ext_vector_type(4))) float floatx4;
typedef unsigned long long u64;

__device__ __forceinline__ unsigned short f2bf(float f) {
    unsigned int u = __float_as_uint(f);
    u += 0x7FFFu + ((u >> 16) & 1u);   // round-to-nearest-even
    return (unsigned short)(u >> 16);
}

// async global->LDS 16B: lane l's 16B lands at ldsbase + l*16 (wave-uniform base)
__device__ __forceinline__ void gload16(const void* g, void* lds) {
    __builtin_amdgcn_global_load_lds(
        (const __attribute__((address_space(1))) unsigned int*)g,
        (__attribute__((address_space(3))) unsigned int*)lds, 16, 0, 0);
}

// ---- kernel 1 (R8): row role ONLY. The label-compress role + posmask intermediary are
// DELETED -- R2/R6/R7 proved the standalone label pass is structurally issue-bound at
// ~74us regardless of grid shape, MLP depth, or coalescing; labels now stream directly
// into gemm (each element consumed by exactly one block). This kernel: loadedmask
// (binary search), zero cntG/gaccum/gcount, normalize V/T rows -> bf16 (R5-exact).
__global__ __launch_bounds__(256) void prep_rows(
    const float* __restrict__ V, const float* __restrict__ T,
    const int* __restrict__ ids,
    u64* __restrict__ loadedmask, unsigned int* __restrict__ cntG,
    unsigned short* __restrict__ Vb, unsigned short* __restrict__ Tb,
    float* __restrict__ gaccum, unsigned int* __restrict__ gcount,
    int B, int C, int n_loaded, int WPR) {
    const int tid  = threadIdx.x;
    const int lane = tid & 63;
    int ptid = blockIdx.x * 256 + tid;
    if (ptid == 0) { *gcount = 0u; *gaccum = 0.f; }   // zero reduce scratch each call
    if (ptid < B) cntG[ptid] = 0u;                    // zero per-row pos counts
    if (ptid < WPR) {
        int base = ptid << 6;
        int lo = 0, hi = n_loaded;
        while (lo < hi) { int mid = (lo + hi) >> 1; if (ids[mid] < base) lo = mid + 1; else hi = mid; }
        u64 m = 0;
        for (int i = lo; i < n_loaded; ++i) {
            int v = ids[i]; if (v >= base + 64) break;
            m |= 1ull << (v - base);
        }
        loadedmask[ptid] = m;
    }
    int wave = ptid >> 6;
    if (wave >= B + C) return;   // whole wave uniform
    bool isV = wave < B;
    const float* src = isV ? (V + (size_t)wave * D_DIM)
                           : (T + (size_t)(wave - B) * D_DIM);
    float4 x = ((const float4*)src)[lane];
    float ss = x.x * x.x + x.y * x.y + x.z * x.z + x.w * x.w;
    #pragma unroll
    for (int off = 32; off > 0; off >>= 1) ss += __shfl_xor(ss, off);
    float nrm = sqrtf(ss);
    float s = isV ? (1.0f / nrm) : (1.0f / (1e-6f + nrm));   // eps on text norms only
    ushort4 o;
    o.x = f2bf(x.x * s); o.y = f2bf(x.y * s);
    o.z = f2bf(x.z * s); o.w = f2bf(x.w * s);
    unsigned short* dst = isV ? (Vb + (size_t)wave * D_DIM)
                              : (Tb + (size_t)(wave - B) * D_DIM);
    ((ushort4*)dst)[lane] = o;
}

// ---- kernel 2 (R8): MFMA S-tile + DIRECT label read --------------------------------
// Each block reads its own 128x128 label patch (64KB, read exactly once grid-wide):
// lane l of wave w owns row wm+l over the wave's 64-col window -> one u64 raw mask,
// built from 16 guarded int4 loads issued BEFORE the K-loop (latency overlaps the
// prologue + first K-steps; VMEM pipe is otherwise idle during MFMA). Epilogue gets
// each frag-row's mask via __shfl. Per-row positive counts -> sCnt (LDS) -> cntG.
__global__ __launch_bounds__(256) void gemm_fused(
    const unsigned short* __restrict__ Vb, const unsigned short* __restrict__ Tb,
    const int* __restrict__ label, const u64* __restrict__ loadedmask,
    float* __restrict__ denomP, float* __restrict__ posP,
    unsigned int* __restrict__ cntG, int C, int WPR) {
    __shared__ unsigned short As[2][TM * BK];   // 2 x 8 KB double buffer
    __shared__ unsigned short Bs[2][TN * BK];   // 2 x 8 KB
    __shared__ float sDen[TM], sPos[TM];
    __shared__ int sCnt[TM];

    const int tid  = threadIdx.x;
    const int lane = tid & 63;
    const int w    = tid >> 6;
    const int m0 = blockIdx.x * TM;
    const int n0 = blockIdx.y * TN;

    if (tid < TM) { sDen[tid] = 0.f; sPos[tid] = 0.f; sCnt[tid] = 0; }

    // ---- wave mapping: 2x2 waves, each 64x64 via 4x4 frags of 16x16x32
    const int wm = (w >> 1) * 64;
    const int wn = (w & 1) * 64;
    const int fr = lane & 15;
    const int quad = lane >> 4;

    // ---- label patch -> per-lane raw mask (row = m0+wm+lane, cols [n0+wn, +64))
    const u64 loadedw = loadedmask[(n0 + wn) >> 6];
    const int* lp = label + (size_t)(m0 + wm + lane) * C;
    const int nBase = n0 + wn;
    u64 praw = 0;
    #pragma unroll
    for (int k = 0; k < 16; ++k) {
        const int col0 = nBase + 4 * k;       // wave-uniform per k
        unsigned int nib = 0;
        if (col0 + 3 < C) {
            int4 v = *(const int4*)(lp + col0);
            nib = (v.x ? 1u : 0u) | (v.y ? 2u : 0u) | (v.z ? 4u : 0u) | (v.w ? 8u : 0u);
        } else {                               // boundary word (wave-uniform branch)
            if (col0 + 0 < C && lp[col0 + 0]) nib |= 1u;
            if (col0 + 1 < C && lp[col0 + 1]) nib |= 2u;
            if (col0 + 2 < C && lp[col0 + 2]) nib |= 4u;
            if (col0 + 3 < C && lp[col0 + 3]) nib |= 8u;
        }
        praw |= (u64)nib << (4 * k);
    }

    // ---- async-staging addresses: wave w covers tile rows [w*32, w*32+32)
    const int sra = lane >> 2;          // row within 16-row group
    const int kc  = (lane & 3) * 8;     // 16B k-chunk
    int ga  = m0 + w * 32 + sra;
    int gb0 = n0 + w * 32 + sra;
    int gb1 = gb0 + 16;
    if (gb0 >= C) gb0 = C - 1;          // OOB rows: valid address, masked in epilogue
    if (gb1 >= C) gb1 = C - 1;
    const unsigned short* gA0 = Vb + (size_t)ga * D_DIM + kc;
    const unsigned short* gA1 = gA0 + (size_t)16 * D_DIM;
    const unsigned short* gB0 = Tb + (size_t)gb0 * D_DIM + kc;
    const unsigned short* gB1 = Tb + (size_t)gb1 * D_DIM + kc;
    const int lofsA = w * 32 * BK;      // wave-uniform LDS offsets (elements)
    const int lofsB = w * 32 * BK;

    floatx4 acc[4][4];
    #pragma unroll
    for (int mi = 0; mi < 4; mi++)
        #pragma unroll
        for (int ni = 0; ni < 4; ni++) acc[mi][ni] = (floatx4)0.f;

    // prologue: stage tile 0 into buffer 0, drain, barrier
    gload16(gA0, &As[0][lofsA]);
    gload16(gA1, &As[0][lofsA + 16 * BK]);
    gload16(gB0, &Bs[0][lofsB]);
    gload16(gB1, &Bs[0][lofsB + 16 * BK]);
    __syncthreads();

    #pragma unroll
    for (int kt = 0; kt < D_DIM / BK; ++kt) {
        const int cur = kt & 1;          // compile-time under full unroll
        if (kt < D_DIM / BK - 1) {       // stage NEXT tile into the other buffer
            const int kb = (kt + 1) * BK;
            gload16(gA0 + kb, &As[cur ^ 1][lofsA]);
            gload16(gA1 + kb, &As[cur ^ 1][lofsA + 16 * BK]);
            gload16(gB0 + kb, &Bs[cur ^ 1][lofsB]);
            gload16(gB1 + kb, &Bs[cur ^ 1][lofsB + 16 * BK]);
        }
        short8 af[4], bf[4];
        #pragma unroll
        for (int mi = 0; mi < 4; mi++)
            af[mi] = *(const short8*)&As[cur][(wm + mi * 16 + fr) * BK + quad * 8];
        #pragma unroll
        for (int ni = 0; ni < 4; ni++)
            bf[ni] = *(const short8*)&Bs[cur][(wn + ni * 16 + fr) * BK + quad * 8];
        #pragma unroll
        for (int mi = 0; mi < 4; mi++)
            #pragma unroll
            for (int ni = 0; ni < 4; ni++)
                acc[mi][ni] = __builtin_amdgcn_mfma_f32_16x16x32_bf16(
                    af[mi], bf[ni], acc[mi][ni], 0, 0, 0);
        __syncthreads();                 // drains this step's stage; swap point
    }

    // ---- epilogue: D layout row = quad*4 + reg, col = lane&15 per 16x16 frag.
    atomicAdd(&sCnt[wm + lane], (int)__popcll(praw & loadedw));  // row pos-count (this word)
    #pragma unroll
    for (int mi = 0; mi < 4; mi++) {
        #pragma unroll
        for (int i = 0; i < 4; i++) {
            const int rloc = mi * 16 + quad * 4 + i;
            const int mloc = wm + rloc;
            const u64 pr = __shfl(praw, rloc);   // row rloc's raw mask (from its lane)
            const u64 posw = pr & loadedw;
            const u64 negw = loadedw & ~pr;
            float den = 0.f, pos = 0.f;
            #pragma unroll
            for (int ni = 0; ni < 4; ni++) {
                const float s = acc[mi][ni][i];
                const int bit = ni * 16 + fr;
                if ((negw >> bit) & 1) den += __expf(s);
                if ((posw >> bit) & 1) pos += s;
            }
            #pragma unroll
            for (int off = 8; off >= 1; off >>= 1) {   // reduce 16-lane quad row
                den += __shfl_xor(den, off);
                pos += __shfl_xor(pos, off);
            }
            if (fr == 0) {
                if (den != 0.f) atomicAdd(&sDen[mloc], den);
                if (pos != 0.f) atomicAdd(&sPos[mloc], pos);
            }
        }
    }
    __syncthreads();
    if (tid < TM) {   // row-major partials: [row][n-block] for coalesced reduce
        denomP[(size_t)(m0 + tid) * NBP + blockIdx.y] = sDen[tid];
        posP[(size_t)(m0 + tid) * NBP + blockIdx.y]   = sPos[tid];
        if (sCnt[tid]) atomicAdd(&cntG[m0 + tid], (unsigned int)sCnt[tid]);
    }
}

// ---- kernel 3: reduce rows + last-block computes the final mean ---------------------
__global__ void reduce_rows(const float* __restrict__ denomP, const float* __restrict__ posP,
                            const unsigned int* __restrict__ cntG,
                            float* __restrict__ gaccum, unsigned int* __restrict__ gcount,
                            float* __restrict__ out, int B, int NB) {
    __shared__ float bsum[4];
    int wv   = threadIdx.x >> 6;
    int row  = blockIdx.x * 4 + wv;
    int lane = threadIdx.x & 63;
    float den = 0.f, pos = 0.f;
    if (row < B) {
        for (int bn = lane; bn < NB; bn += 64) {   // contiguous within row: coalesced
            den += denomP[(size_t)row * NBP + bn];
            pos += posP[(size_t)row * NBP + bn];
        }
        #pragma unroll
        for (int off = 32; off > 0; off >>= 1) {
            den += __shfl_xor(den, off);
            pos += __shfl_xor(pos, off);
        }
    }
    if (lane == 0) bsum[wv] = (row < B) ? (logf(den) - pos / (float)cntG[row]) : 0.f;
    __syncthreads();
    if (threadIdx.x == 0) {
        float s = bsum[0] + bsum[1] + bsum[2] + bsum[3];
        atomicAdd(gaccum, s);            // 128 ops total: contention negligible
        __threadfence();
        unsigned int old = atomicAdd(gcount, 1u);
        if (old == gridDim.x - 1) {      // last block: all adds complete & visible
            float tot = atomicAdd(gaccum, 0.0f);   // atomic read-back
            out[0] = tot / (float)B;
        }
    }
}

extern "C" void kernel_launch(void* const* d_in, const int* in_sizes, int n_in,
                              void* d_out, int out_size, void* d_ws, size_t ws_size,
                              hipStream_t stream) {
    const float* V     = (const float*)d_in[0];
    const float* T     = (const float*)d_in[1];
    const int*   label = (const int*)d_in[2];
    const int*   ids   = (const int*)d_in[3];
    int B = in_sizes[0] / D_DIM;   // 512
    int C = in_sizes[1] / D_DIM;   // 50000
    int n_loaded = in_sizes[3];    // 40000
    int WPR = (C + 63) >> 6;       // mask words per row (782)
    int NB  = (C + TN - 1) / TN;   // n-blocks (391)

    // ws layout (bytes) -- posmask deleted (R8):
    //   0        : gaccum [1 f], gcount [1 u32]
    //   64       : cntG [512 u32]                   (ends 2112)
    //   4096     : loadedmask [782 u64]             (ends 10352)
    //   16384    : Vb [512*256 bf16]                (262,144 -> ends 278,528)
    //   278528   : Tb [50000*256 bf16]              (25.6 MB -> ends 25,878,528)
    //   25878528 : denomP [512*NBP f]               (802,816 -> ends 26,681,344)
    //   26681344 : posP                             (ends 27,484,160)
    char* ws = (char*)d_ws;
    float*        gaccum = (float*)(ws + 0);
    unsigned int* gcount = (unsigned int*)(ws + 8);
    unsigned int* cntG   = (unsigned int*)(ws + 64);
    u64*   loadedmask = (u64*)(ws + 4096);
    unsigned short* Vb = (unsigned short*)(ws + 16384);
    unsigned short* Tb = (unsigned short*)(ws + 278528);
    float* denomP  = (float*)(ws + 25878528);
    float* posP    = (float*)(ws + 26681344);

    int prep_blocks = ((B + C) * 64 + 255) / 256;    // 12628
    prep_rows<<<prep_blocks, 256, 0, stream>>>(
        V, T, ids, loadedmask, cntG, Vb, Tb, gaccum, gcount,
        B, C, n_loaded, WPR);

    dim3 grid(B / TM, NB);   // m fastest: 4 blocks share one T-tile
    gemm_fused<<<grid, 256, 0, stream>>>(Vb, Tb, label, loadedmask,
                                         denomP, posP, cntG, C, WPR);

    reduce_rows<<<(B + 3) / 4, 256, 0, stream>>>(denomP, posP, cntG,
                                                 gaccum, gcount, (float*)d_out, B, NB);
}